// Round 8
// baseline (244.168 us; speedup 1.0000x reference)
//
#include <hip/hip_runtime.h>
#include <stdint.h>

#define BB     64
#define CC     12
#define LL     2048
#define KERNSZ 9
#define KK     8     // kernels per group
#define GG     32    // groups per branch (_G)
#define NPER   6
#define NDIL   8
#define PAD    128   // halo covers D<=32 exactly; D=64/128 clamp into zeroed pads
#define MAIN   2048
#define BUFSZ  (PAD + MAIN + PAD)   // 2304 floats = 9216 B per wave
#define WPB    2                    // 18432 B/block -> 8 blocks/CU = 16 waves/CU

typedef float f2 __attribute__((ext_vector_type(2)));
typedef float f4 __attribute__((ext_vector_type(4)));

// acc.{lo,hi} += t.lo * w.{lo,hi}   (tap broadcast via op_sel_hi[0]=0;
// weights are a wave-uniform SGPR pair -> no VGPR replication, no spill)
__device__ __forceinline__ void pk_fma_bcast(f2& acc, const f2& t, uint64_t wpair) {
    asm("v_pk_fma_f32 %0, %1, %2, %0 op_sel:[0,0,0] op_sel_hi:[0,1,1]"
        : "+v"(acc) : "v"(t), "s"(wpair));
}
__device__ __forceinline__ f2 pk_mul_bcast(const f2& t, uint64_t wpair) {
    f2 d;
    asm("v_pk_mul_f32 %0, %1, %2 op_sel:[0,0] op_sel_hi:[0,1]"
        : "=v"(d) : "v"(t), "s"(wpair));
    return d;
}
// guaranteed 3-input max/min
__device__ __forceinline__ float max3f(float a, float b, float c) {
    float d; asm("v_max3_f32 %0, %1, %2, %3" : "=v"(d) : "v"(a), "v"(b), "v"(c)); return d;
}
__device__ __forceinline__ float min3f(float a, float b, float c) {
    float d; asm("v_min3_f32 %0, %1, %2, %3" : "=v"(d) : "v"(a), "v"(b), "v"(c)); return d;
}

// Load the 9 taps for output position pos into t. For 4*D > PAD the OOB taps
// clamp into the zeroed pads (1 v_max/v_min per edge tap) -> tap reads 0,
// identical contribution to full-width zero padding. Same in-loop constexpr
// structure as the proven R1/R5 D=128 path; no loop splitting.
template <int D>
__device__ __forceinline__ void load_taps(const float* __restrict__ sel,
                                          int pos, f2 (&t)[KERNSZ]) {
    if constexpr (4 * D > PAD) {
        #pragma unroll
        for (int j = 0; j < KERNSZ; ++j) {
            int off = pos + (j - 4) * D;
            if (j < 4) off = (off < -PAD) ? -PAD : off;
            if (j > 4) off = (off > MAIN + PAD - 1) ? (MAIN + PAD - 1) : off;
            t[j].x = sel[off];
        }
    } else {
        const float* p = sel + pos - 4 * D;   // pads make all 9 taps valid
        #pragma unroll
        for (int j = 0; j < KERNSZ; ++j)
            t[j].x = p[j * D];
    }
}

// Compute + accumulate for one 64-position slab whose taps are already in t.
// All-packed conv (R5 structure — proven best; dual-pipe split was null in R7).
__device__ __forceinline__ void conv_body(
    const f2 (&t)[KERNSZ], const uint64_t (&wp)[4][KERNSZ],
    bool kill63, int lane, float (&accM)[KK], uint32_t (&cnt)[KK])
{
    f2 v2[4];                              // (v0,v1)(v2,v3)(v4,v5)(v6,v7)
    #pragma unroll
    for (int c = 0; c < 4; ++c)
        v2[c] = pk_mul_bcast(t[0], wp[c][0]);
    #pragma unroll
    for (int j = 1; j < KERNSZ; ++j)
        #pragma unroll
        for (int c = 0; c < 4; ++c)
            pk_fma_bcast(v2[c], t[j], wp[c][j]);

    float v[KK] = { v2[0].x, v2[0].y, v2[1].x, v2[1].y,
                    v2[2].x, v2[2].y, v2[3].x, v2[3].y };

    float ma = max3f(v[0], v[1], v[2]);
    float mb = max3f(v[3], v[4], v[5]);
    float mc = max3f(v[6], v[7], ma);
    float mv = fmaxf(mb, mc);
    float na = min3f(v[0], v[1], v[2]);
    float nb = min3f(v[3], v[4], v[5]);
    float nc = min3f(v[6], v[7], na);
    float nv = fminf(nb, nc);

    // only invalid output position: pos==2047 on diff branch.
    // NaN never compares equal -> contributes nothing below.
    if (kill63 && lane == 63) {
        const float NANF = __uint_as_float(0x7fc00000u);
        mv = NANF; nv = NANF;
    }

    // argmin count via ballot: v_cmp (VALU) + bcnt/add on the idle SALU pipe;
    // cnt[] is wave-uniform -> SGPRs, no tail butterfly needed
    #pragma unroll
    for (int k = 0; k < KK; ++k)
        cnt[k] += (uint32_t)__popcll(__ballot(v[k] == nv));

    // count_max accumulate via v_cmpx + predicated add: 2 VALU per k.
    // Winning lanes (v[k] bit-equals mv) add mv under the exec mask.
    uint64_t es;
    asm volatile(
        "s_mov_b64 %[es], exec\n\t"
        "v_cmpx_eq_f32 vcc, %[x0], %[mv]\n\t"
        "v_add_f32 %[a0], %[a0], %[mv]\n\t"
        "s_mov_b64 exec, %[es]\n\t"
        "v_cmpx_eq_f32 vcc, %[x1], %[mv]\n\t"
        "v_add_f32 %[a1], %[a1], %[mv]\n\t"
        "s_mov_b64 exec, %[es]\n\t"
        "v_cmpx_eq_f32 vcc, %[x2], %[mv]\n\t"
        "v_add_f32 %[a2], %[a2], %[mv]\n\t"
        "s_mov_b64 exec, %[es]\n\t"
        "v_cmpx_eq_f32 vcc, %[x3], %[mv]\n\t"
        "v_add_f32 %[a3], %[a3], %[mv]\n\t"
        "s_mov_b64 exec, %[es]\n\t"
        "v_cmpx_eq_f32 vcc, %[x4], %[mv]\n\t"
        "v_add_f32 %[a4], %[a4], %[mv]\n\t"
        "s_mov_b64 exec, %[es]\n\t"
        "v_cmpx_eq_f32 vcc, %[x5], %[mv]\n\t"
        "v_add_f32 %[a5], %[a5], %[mv]\n\t"
        "s_mov_b64 exec, %[es]\n\t"
        "v_cmpx_eq_f32 vcc, %[x6], %[mv]\n\t"
        "v_add_f32 %[a6], %[a6], %[mv]\n\t"
        "s_mov_b64 exec, %[es]\n\t"
        "v_cmpx_eq_f32 vcc, %[x7], %[mv]\n\t"
        "v_add_f32 %[a7], %[a7], %[mv]\n\t"
        "s_mov_b64 exec, %[es]"
        : [es]"=&s"(es),
          [a0]"+v"(accM[0]), [a1]"+v"(accM[1]),
          [a2]"+v"(accM[2]), [a3]"+v"(accM[3]),
          [a4]"+v"(accM[4]), [a5]"+v"(accM[5]),
          [a6]"+v"(accM[6]), [a7]"+v"(accM[7])
        : [x0]"v"(v[0]), [x1]"v"(v[1]), [x2]"v"(v[2]), [x3]"v"(v[3]),
          [x4]"v"(v[4]), [x5]"v"(v[5]), [x6]"v"(v[6]), [x7]"v"(v[7]),
          [mv]"v"(mv)
        : "vcc");
}

// Phase 2: simple loop; unroll 8 so tap addresses fold into immediate offsets
// and loop overhead amortizes.
template <int D>
__device__ __forceinline__ void run_phase2(
    const float* __restrict__ sel, int lane, int dif,
    const uint64_t (&wp)[4][KERNSZ], float (&accM)[KK], uint32_t (&cnt)[KK])
{
    #pragma unroll 8
    for (int q = 0; q < 32; ++q) {
        f2 t[KERNSZ];
        load_taps<D>(sel, q * 64 + lane, t);
        conv_body(t, wp, dif && (q == 31), lane, accM, cnt);
    }
}

__global__ __launch_bounds__(128, 4) void hydra_kernel(
    const float* __restrict__ X,    // [B, C, L]
    const float* __restrict__ W,    // [NDIL, 2, KK*GG, 1, KERNSZ]
    const int*   __restrict__ I,    // [NDIL, 2, GG, NPER]
    float*       __restrict__ out)  // [B, 8192]
{
    __shared__ float lds[WPB][BUFSZ];   // waves independent; no barriers needed

    const int tid  = threadIdx.x;
    const int wave = tid >> 6;
    const int lane = tid & 63;
    const int wid  = blockIdx.x * WPB + wave;   // 0..32767
    // task decode: wid = b*512 + di*64 + dif*32 + g
    const int b   = wid >> 9;
    const int r   = wid & 511;
    const int di  = r >> 6;
    const int r2  = r & 63;
    const int dif = r2 >> 5;
    const int g   = r2 & 31;

    float* buf = lds[wave];
    float* sel = buf + PAD;

    // ---- zero halo pads (64 lanes x float2 = 128 floats per side) ----
    {
        f2 z = {0.0f, 0.0f};
        ((f2*)buf)[lane]                = z;   // left pad
        ((f2*)(buf + PAD + MAIN))[lane] = z;   // right pad
    }

    // ---- phase 1: channel-subset sum S into sel[0..2047] (dwordx4 loads) ----
    const int* Ig = I + ((size_t)((di * 2 + dif) * GG + g)) * NPER;
    const float* xb = X + (size_t)b * CC * LL;
    const f4* c0 = (const f4*)(xb + Ig[0] * LL);
    const f4* c1 = (const f4*)(xb + Ig[1] * LL);
    const f4* c2 = (const f4*)(xb + Ig[2] * LL);
    const f4* c3 = (const f4*)(xb + Ig[3] * LL);
    const f4* c4 = (const f4*)(xb + Ig[4] * LL);
    const f4* c5 = (const f4*)(xb + Ig[5] * LL);
    f4* sel4 = (f4*)sel;

    #pragma unroll 2
    for (int q = 0; q < 8; ++q) {
        int idx = q * 64 + lane;                  // float4 index, 512 quads total
        f4 s = (c0[idx] + c1[idx]) + (c2[idx] + c3[idx]) + (c4[idx] + c5[idx]);
        sel4[idx] = s;
    }

    if (dif) {
        // in-place wave-synchronous forward diff, vectorized. Per-wave LDS ops
        // are in program order: all lanes' reads of iteration q issue before
        // its writes; the extra scalar read at idx*4+4 targets data written
        // only later (lane l+1 this iter, or region of iter q+1).
        #pragma unroll 2
        for (int q = 0; q < 8; ++q) {
            int idx = q * 64 + lane;              // quad index
            f4 a  = sel4[idx];
            float an = sel[idx * 4 + 4];          // sel[2048] is the zeroed pad
            f4 v;
            v.x = a.y - a.x;
            v.y = a.z - a.y;
            v.z = a.w - a.z;
            v.w = (idx == 511) ? 0.0f : (an - a.w);   // pos 2047 -> 0
            sel4[idx] = v;
        }
    }

    // ---- weights: wave-uniform scalar loads, packed into SGPR pairs ----
    const float* Wg = W + (size_t)((di * 2 + dif) * (KK * GG) + g * KK) * KERNSZ;
    uint64_t wp[4][KERNSZ];   // wp[c][j] = (w[2c][j], w[2c+1][j])
    #pragma unroll
    for (int c = 0; c < 4; ++c)
        #pragma unroll
        for (int j = 0; j < KERNSZ; ++j) {
            uint32_t lo = __float_as_uint(Wg[(2 * c)     * KERNSZ + j]);
            uint32_t hi = __float_as_uint(Wg[(2 * c + 1) * KERNSZ + j]);
            wp[c][j] = (uint64_t)lo | ((uint64_t)hi << 32);
        }

    float    accM[KK];
    uint32_t cnt[KK];
    #pragma unroll
    for (int k = 0; k < KK; ++k) { accM[k] = 0.0f; cnt[k] = 0u; }

    switch (di) {   // block-uniform branch (di uniform per wave; branch per wave)
        case 0: run_phase2<1>  (sel, lane, dif, wp, accM, cnt); break;
        case 1: run_phase2<2>  (sel, lane, dif, wp, accM, cnt); break;
        case 2: run_phase2<4>  (sel, lane, dif, wp, accM, cnt); break;
        case 3: run_phase2<8>  (sel, lane, dif, wp, accM, cnt); break;
        case 4: run_phase2<16> (sel, lane, dif, wp, accM, cnt); break;
        case 5: run_phase2<32> (sel, lane, dif, wp, accM, cnt); break;
        case 6: run_phase2<64> (sel, lane, dif, wp, accM, cnt); break;
        default: run_phase2<128>(sel, lane, dif, wp, accM, cnt); break;
    }

    // ---- tail: butterfly-reduce accM only; cnt is already wave-uniform ----
    float* o = out + (size_t)b * 8192 + (size_t)((di * 2 + dif) * 2) * 256 + g * KK;
    #pragma unroll
    for (int k = 0; k < KK; ++k) {
        float a = accM[k];
        #pragma unroll
        for (int off = 32; off > 0; off >>= 1)
            a += __shfl_xor(a, off, 64);
        if (lane == 0) {
            o[k]       = a;               // count_max block (which=0)
            o[256 + k] = (float)cnt[k];   // count_min block (which=1)
        }
    }
}

extern "C" void kernel_launch(void* const* d_in, const int* in_sizes, int n_in,
                              void* d_out, int out_size, void* d_ws, size_t ws_size,
                              hipStream_t stream) {
    const float* X = (const float*)d_in[0];
    const float* W = (const float*)d_in[1];
    const int*   I = (const int*)d_in[2];
    float* out = (float*)d_out;

    const int total_waves = BB * NDIL * 2 * GG;       // 32768
    const int blocks = total_waves / WPB;             // 16384
    hydra_kernel<<<blocks, 128, 0, stream>>>(X, W, I, out);
}

// Round 10
// 230.568 us; speedup vs baseline: 1.0590x; 1.0590x over previous
//
#include <hip/hip_runtime.h>
#include <stdint.h>

#define BB     64
#define CC     12
#define LL     2048
#define KERNSZ 9
#define KK     8     // kernels per group
#define GG     32    // groups per branch (_G)
#define NPER   6
#define NDIL   8
#define PAD    256   // halo covers D<=64 exactly; D=128 uses clamped taps
#define MAIN   2048
#define BUFSZ  (PAD + MAIN + PAD)   // 2560 floats = 10240 B per block (1 wave)

typedef float f2 __attribute__((ext_vector_type(2)));
typedef float f4 __attribute__((ext_vector_type(4)));

// Position-pair conv ops: acc.{lo,hi} += t.{lo,hi} * w  where w is ONE half of
// a wave-uniform SGPR pair (VOP3P packed-f32 sources must be 64b-aligned pairs
// — a single SGPR is an invalid operand, hence the pair + op_sel selection).
// _wlo: both result halves read src1.lo (even tap); _whi: src1.hi (odd tap).
__device__ __forceinline__ void pk_fma_wlo(f2& acc, const f2& t, uint64_t wpair) {
    asm("v_pk_fma_f32 %0, %1, %2, %0 op_sel:[0,0,0] op_sel_hi:[1,0,1]"
        : "+v"(acc) : "v"(t), "s"(wpair));
}
__device__ __forceinline__ void pk_fma_whi(f2& acc, const f2& t, uint64_t wpair) {
    asm("v_pk_fma_f32 %0, %1, %2, %0 op_sel:[0,1,0] op_sel_hi:[1,1,1]"
        : "+v"(acc) : "v"(t), "s"(wpair));
}
__device__ __forceinline__ f2 pk_mul_wlo(const f2& t, uint64_t wpair) {
    f2 d;
    asm("v_pk_mul_f32 %0, %1, %2 op_sel:[0,0] op_sel_hi:[1,0]"
        : "=v"(d) : "v"(t), "s"(wpair));
    return d;
}
// guaranteed 3-input max/min
__device__ __forceinline__ float max3f(float a, float b, float c) {
    float d; asm("v_max3_f32 %0, %1, %2, %3" : "=v"(d) : "v"(a), "v"(b), "v"(c)); return d;
}
__device__ __forceinline__ float min3f(float a, float b, float c) {
    float d; asm("v_min3_f32 %0, %1, %2, %3" : "=v"(d) : "v"(a), "v"(b), "v"(c)); return d;
}

// Load taps for positions (posA, posA+64) into t pairs. x/y are 64 dwords
// apart -> compiler can merge into ds_read2_b32.
template <int D>
__device__ __forceinline__ void load_taps2(const float* __restrict__ sel,
                                           int posA, f2 (&t)[KERNSZ]) {
    if constexpr (D == 128) {
        // halo is only 256; clamp OOB taps into the zeroed pads -> tap=0,
        // identical contribution to what 512-wide zero padding gave.
        #pragma unroll
        for (int j = 0; j < KERNSZ; ++j) {
            int offA = posA + (j - 4) * D;
            int offB = offA + 64;
            if (j < 4) { offA = (offA < -PAD) ? -PAD : offA;
                         offB = (offB < -PAD) ? -PAD : offB; }
            if (j > 4) { offA = (offA > MAIN + PAD - 1) ? (MAIN + PAD - 1) : offA;
                         offB = (offB > MAIN + PAD - 1) ? (MAIN + PAD - 1) : offB; }
            t[j].x = sel[offA];
            t[j].y = sel[offB];
        }
    } else {
        const float* p = sel + posA - 4 * D;   // pads make all 9 taps valid
        #pragma unroll
        for (int j = 0; j < KERNSZ; ++j) {
            t[j].x = p[j * D];
            t[j].y = p[j * D + 64];
        }
    }
}

// count_max accumulate via v_cmpx + predicated add: 2 VALU per k.
// Winning lanes (v[k] bit-equals mv) add mv under the exec mask.
__device__ __forceinline__ void accum_max8(
    float (&accM)[KK], const float* v, float mv)
{
    uint64_t es;
    asm volatile(
        "s_mov_b64 %[es], exec\n\t"
        "v_cmpx_eq_f32 vcc, %[x0], %[mv]\n\t"
        "v_add_f32 %[a0], %[a0], %[mv]\n\t"
        "s_mov_b64 exec, %[es]\n\t"
        "v_cmpx_eq_f32 vcc, %[x1], %[mv]\n\t"
        "v_add_f32 %[a1], %[a1], %[mv]\n\t"
        "s_mov_b64 exec, %[es]\n\t"
        "v_cmpx_eq_f32 vcc, %[x2], %[mv]\n\t"
        "v_add_f32 %[a2], %[a2], %[mv]\n\t"
        "s_mov_b64 exec, %[es]\n\t"
        "v_cmpx_eq_f32 vcc, %[x3], %[mv]\n\t"
        "v_add_f32 %[a3], %[a3], %[mv]\n\t"
        "s_mov_b64 exec, %[es]\n\t"
        "v_cmpx_eq_f32 vcc, %[x4], %[mv]\n\t"
        "v_add_f32 %[a4], %[a4], %[mv]\n\t"
        "s_mov_b64 exec, %[es]\n\t"
        "v_cmpx_eq_f32 vcc, %[x5], %[mv]\n\t"
        "v_add_f32 %[a5], %[a5], %[mv]\n\t"
        "s_mov_b64 exec, %[es]\n\t"
        "v_cmpx_eq_f32 vcc, %[x6], %[mv]\n\t"
        "v_add_f32 %[a6], %[a6], %[mv]\n\t"
        "s_mov_b64 exec, %[es]\n\t"
        "v_cmpx_eq_f32 vcc, %[x7], %[mv]\n\t"
        "v_add_f32 %[a7], %[a7], %[mv]\n\t"
        "s_mov_b64 exec, %[es]"
        : [es]"=&s"(es),
          [a0]"+v"(accM[0]), [a1]"+v"(accM[1]),
          [a2]"+v"(accM[2]), [a3]"+v"(accM[3]),
          [a4]"+v"(accM[4]), [a5]"+v"(accM[5]),
          [a6]"+v"(accM[6]), [a7]"+v"(accM[7])
        : [x0]"v"(v[0]), [x1]"v"(v[1]), [x2]"v"(v[2]), [x3]"v"(v[3]),
          [x4]"v"(v[4]), [x5]"v"(v[5]), [x6]"v"(v[6]), [x7]"v"(v[7]),
          [mv]"v"(mv)
        : "vcc");
}

// Per-position epilogue: max/min trees, optional NaN kill, count accumulation.
__device__ __forceinline__ void epilogue8(
    const float* v, bool kill, int lane,
    float (&accM)[KK], uint32_t (&cnt)[KK])
{
    float ma = max3f(v[0], v[1], v[2]);
    float mb = max3f(v[3], v[4], v[5]);
    float mc = max3f(v[6], v[7], ma);
    float mv = fmaxf(mb, mc);
    float na = min3f(v[0], v[1], v[2]);
    float nb = min3f(v[3], v[4], v[5]);
    float nc = min3f(v[6], v[7], na);
    float nv = fminf(nb, nc);

    // only invalid output position: pos==2047 on diff branch.
    // NaN never compares equal -> contributes nothing below.
    if (kill && lane == 63) {
        const float NANF = __uint_as_float(0x7fc00000u);
        mv = NANF; nv = NANF;
    }

    // argmin count via ballot: v_cmp (VALU) + bcnt/add on the idle SALU pipe;
    // cnt[] is wave-uniform -> SGPRs, no tail butterfly needed
    #pragma unroll
    for (int k = 0; k < KK; ++k)
        cnt[k] += (uint32_t)__popcll(__ballot(v[k] == nv));

    accum_max8(accM, v, mv);
}

// Compute + accumulate for a PAIR of 64-position slabs (posA, posA+64).
// 8 kernel-chains of 9 pk ops each compute both positions at once — same VALU
// per position as R5's champion, half the iterations / tap loads.
// Weights: wp[k][jj] = (w[k][2jj], w[k][2jj+1]); w8[c] = (w[2c][8], w[2c+1][8]).
__device__ __forceinline__ void conv_pair(
    const f2 (&t)[KERNSZ], const uint64_t (&wp)[KK][4], const uint64_t (&w8)[4],
    bool killB, int lane, float (&accM)[KK], uint32_t (&cnt)[KK])
{
    f2 v2[KK];
    #pragma unroll
    for (int k = 0; k < KK; ++k)
        v2[k] = pk_mul_wlo(t[0], wp[k][0]);          // tap 0
    #pragma unroll
    for (int k = 0; k < KK; ++k)
        pk_fma_whi(v2[k], t[1], wp[k][0]);           // tap 1
    #pragma unroll
    for (int jj = 1; jj < 4; ++jj) {
        #pragma unroll
        for (int k = 0; k < KK; ++k)
            pk_fma_wlo(v2[k], t[2 * jj], wp[k][jj]);     // even tap
        #pragma unroll
        for (int k = 0; k < KK; ++k)
            pk_fma_whi(v2[k], t[2 * jj + 1], wp[k][jj]); // odd tap
    }
    #pragma unroll
    for (int c = 0; c < 4; ++c) {                    // tap 8
        pk_fma_wlo(v2[2 * c],     t[8], w8[c]);
        pk_fma_whi(v2[2 * c + 1], t[8], w8[c]);
    }

    float vx[KK] = { v2[0].x, v2[1].x, v2[2].x, v2[3].x,
                     v2[4].x, v2[5].x, v2[6].x, v2[7].x };
    float vy[KK] = { v2[0].y, v2[1].y, v2[2].y, v2[3].y,
                     v2[4].y, v2[5].y, v2[6].y, v2[7].y };

    epilogue8(vx, false, lane, accM, cnt);   // positions posA..posA+63
    epilogue8(vy, killB, lane, accM, cnt);   // positions posA+64..posA+127
}

// Phase 2: 16 pair-iterations (positions p*128+lane and +64).
template <int D>
__device__ __forceinline__ void run_phase2(
    const float* __restrict__ sel, int lane, int dif,
    const uint64_t (&wp)[KK][4], const uint64_t (&w8)[4],
    float (&accM)[KK], uint32_t (&cnt)[KK])
{
    #pragma unroll 4
    for (int p = 0; p < 16; ++p) {
        f2 t[KERNSZ];
        load_taps2<D>(sel, p * 128 + lane, t);
        conv_pair(t, wp, w8, dif && (p == 15), lane, accM, cnt);
    }
}

__global__ __launch_bounds__(64, 4) void hydra_kernel(
    const float* __restrict__ X,    // [B, C, L]
    const float* __restrict__ W,    // [NDIL, 2, KK*GG, 1, KERNSZ]
    const int*   __restrict__ I,    // [NDIL, 2, GG, NPER]
    float*       __restrict__ out)  // [B, 8192]
{
    __shared__ float buf[BUFSZ];    // one wave per block; no barriers needed

    const int lane = threadIdx.x;
    const int wid  = blockIdx.x;    // 0..32767
    // task decode: wid = b*512 + di*64 + dif*32 + g
    const int b   = wid >> 9;
    const int r   = wid & 511;
    const int di  = r >> 6;
    const int r2  = r & 63;
    const int dif = r2 >> 5;
    const int g   = r2 & 31;

    float* sel = buf + PAD;

    // ---- zero halo pads (vectorized: 64 lanes x float4 = 256 floats) ----
    {
        f4 z = {0.0f, 0.0f, 0.0f, 0.0f};
        ((f4*)buf)[lane]                = z;   // left pad
        ((f4*)(buf + PAD + MAIN))[lane] = z;   // right pad
    }

    // ---- phase 1: channel-subset sum S into sel[0..2047] (dwordx4 loads) ----
    const int* Ig = I + ((size_t)((di * 2 + dif) * GG + g)) * NPER;
    const float* xb = X + (size_t)b * CC * LL;
    const f4* c0 = (const f4*)(xb + Ig[0] * LL);
    const f4* c1 = (const f4*)(xb + Ig[1] * LL);
    const f4* c2 = (const f4*)(xb + Ig[2] * LL);
    const f4* c3 = (const f4*)(xb + Ig[3] * LL);
    const f4* c4 = (const f4*)(xb + Ig[4] * LL);
    const f4* c5 = (const f4*)(xb + Ig[5] * LL);
    f4* sel4 = (f4*)sel;

    #pragma unroll 2
    for (int q = 0; q < 8; ++q) {
        int idx = q * 64 + lane;                  // float4 index, 512 quads total
        f4 s = (c0[idx] + c1[idx]) + (c2[idx] + c3[idx]) + (c4[idx] + c5[idx]);
        sel4[idx] = s;
    }

    if (dif) {
        // in-place wave-synchronous forward diff, vectorized. Per-wave LDS ops
        // are in program order: all lanes' reads of iteration q issue before
        // its writes; the extra scalar read at idx*4+4 targets data written
        // only later (lane l+1 this iter, or region of iter q+1).
        #pragma unroll 2
        for (int q = 0; q < 8; ++q) {
            int idx = q * 64 + lane;              // quad index
            f4 a  = sel4[idx];
            float an = sel[idx * 4 + 4];          // sel[2048] is the zeroed pad
            f4 v;
            v.x = a.y - a.x;
            v.y = a.z - a.y;
            v.z = a.w - a.z;
            v.w = (idx == 511) ? 0.0f : (an - a.w);   // pos 2047 -> 0
            sel4[idx] = v;
        }
    }

    // ---- weights: wave-uniform scalar loads, packed into SGPR pairs ----
    const float* Wg = W + (size_t)((di * 2 + dif) * (KK * GG) + g * KK) * KERNSZ;
    uint64_t wp[KK][4];   // wp[k][jj] = (w[k][2jj], w[k][2jj+1]), taps 0..7
    uint64_t w8[4];       // w8[c] = (w[2c][8], w[2c+1][8]), tap 8
    #pragma unroll
    for (int k = 0; k < KK; ++k)
        #pragma unroll
        for (int jj = 0; jj < 4; ++jj) {
            uint32_t lo = __float_as_uint(Wg[k * KERNSZ + 2 * jj]);
            uint32_t hi = __float_as_uint(Wg[k * KERNSZ + 2 * jj + 1]);
            wp[k][jj] = (uint64_t)lo | ((uint64_t)hi << 32);
        }
    #pragma unroll
    for (int c = 0; c < 4; ++c) {
        uint32_t lo = __float_as_uint(Wg[(2 * c)     * KERNSZ + 8]);
        uint32_t hi = __float_as_uint(Wg[(2 * c + 1) * KERNSZ + 8]);
        w8[c] = (uint64_t)lo | ((uint64_t)hi << 32);
    }

    float    accM[KK];
    uint32_t cnt[KK];
    #pragma unroll
    for (int k = 0; k < KK; ++k) { accM[k] = 0.0f; cnt[k] = 0u; }

    switch (di) {   // block-uniform branch
        case 0: run_phase2<1>  (sel, lane, dif, wp, w8, accM, cnt); break;
        case 1: run_phase2<2>  (sel, lane, dif, wp, w8, accM, cnt); break;
        case 2: run_phase2<4>  (sel, lane, dif, wp, w8, accM, cnt); break;
        case 3: run_phase2<8>  (sel, lane, dif, wp, w8, accM, cnt); break;
        case 4: run_phase2<16> (sel, lane, dif, wp, w8, accM, cnt); break;
        case 5: run_phase2<32> (sel, lane, dif, wp, w8, accM, cnt); break;
        case 6: run_phase2<64> (sel, lane, dif, wp, w8, accM, cnt); break;
        default: run_phase2<128>(sel, lane, dif, wp, w8, accM, cnt); break;
    }

    // ---- tail: butterfly-reduce accM only; cnt is already wave-uniform ----
    float* o = out + (size_t)b * 8192 + (size_t)((di * 2 + dif) * 2) * 256 + g * KK;
    #pragma unroll
    for (int k = 0; k < KK; ++k) {
        float a = accM[k];
        #pragma unroll
        for (int off = 32; off > 0; off >>= 1)
            a += __shfl_xor(a, off, 64);
        if (lane == 0) {
            o[k]       = a;               // count_max block (which=0)
            o[256 + k] = (float)cnt[k];   // count_min block (which=1)
        }
    }
}

extern "C" void kernel_launch(void* const* d_in, const int* in_sizes, int n_in,
                              void* d_out, int out_size, void* d_ws, size_t ws_size,
                              hipStream_t stream) {
    const float* X = (const float*)d_in[0];
    const float* W = (const float*)d_in[1];
    const int*   I = (const int*)d_in[2];
    float* out = (float*)d_out;

    const int total_waves = BB * NDIL * 2 * GG;       // 32768
    hydra_kernel<<<total_waves, 64, 0, stream>>>(X, W, I, out);
}